// Round 6
// baseline (73.076 us; speedup 1.0000x reference)
//
#include <hip/hip_runtime.h>
#include <math.h>

#define NB 8
#define NT 4096
#define ND 1024
#define NL 3
#define NO 4
#define NLO 12
#define TWO_PI_D 6.283185307179586476925286766559
#define DT_D 0.1
#define NSTEPS 10
#define THRESH_D 0.3

// ------------- Kernel W-prep: W f32 -> f64 (96 KB, L2-resident) -------------
__global__ __launch_bounds__(256) void k_wprep(const float* __restrict__ W,
                                               double* __restrict__ wsW)
{
    int i = blockIdx.x * 256 + threadIdx.x;
    if (i < NLO * ND) wsW[i] = (double)W[i];
}

// ------------- Kernel A v7: T14 double-buffered LDS x + SGPR W --------------
// Block 512 thr = 8 waves; block owns 64 rows; wave w owns d-slice [128w,128w+128).
// 8 its of 16 d. Per it: (a) prefetch it+1's [64x16] f32 window into regs
// (coalesced 64B/row), (b) ds_read own row's 16 d from current half-tile
// (XOR-swizzled, conflict-free), (c) 192 f64 FMA with W via readfirstlane-
// uniform s_load, (d) ds_write prefetched regs to alternate half (vmcnt lands
// here, after FMAs). Wave-synchronous; no barriers in main loop.
__global__ __launch_bounds__(512, 4) void k_proj(
    const float* __restrict__ x, const double* __restrict__ wsW,
    double* __restrict__ ws_ph, float* __restrict__ ws_s,
    float* __restrict__ ws_c)
{
    __shared__ char buf[65536];               // 8 waves x (2 x 4 KB halves); red overlay
    const int tid = threadIdx.x;
    const int lane = tid & 63;
    const int wid = __builtin_amdgcn_readfirstlane(tid >> 6);   // 0..7, uniform
    const long row0 = (long)blockIdx.x * 64;
    const double* wbase = wsW + wid * 128;    // uniform base -> s_load path
    char* tile = buf + wid * 8192;

    const int rg = lane >> 2;                 // staging row subgroup 0..15
    const int slot = lane & 3;                // 16B slot within 64B row window
    const float* xbase = x + row0 * ND + wid * 128;

    double acc[NLO];
#pragma unroll
    for (int lo = 0; lo < NLO; ++lo) acc[lo] = 0.0;

    float4 fr[4];
    // prologue: load + store it=0 into half 0
#pragma unroll
    for (int p = 0; p < 4; ++p) {
        int r = p * 16 + rg;
        fr[p] = *reinterpret_cast<const float4*>(xbase + (long)r * ND + slot * 4);
    }
#pragma unroll
    for (int p = 0; p < 4; ++p) {
        int r = p * 16 + rg;
        *reinterpret_cast<float4*>(tile + r * 64 + ((slot ^ (r & 3)) * 16)) = fr[p];
    }

#pragma unroll
    for (int it = 0; it < 8; ++it) {
        // (a) prefetch next window into regs (global loads issued early)
        if (it < 7) {
#pragma unroll
            for (int p = 0; p < 4; ++p) {
                int r = p * 16 + rg;
                fr[p] = *reinterpret_cast<const float4*>(
                    xbase + (long)r * ND + (it + 1) * 16 + slot * 4);
            }
        }
        // (b) read own row's 16 d from current half (conflict-free swizzle)
        const char* th = tile + (it & 1) * 4096;
        float4 f[4];
#pragma unroll
        for (int q = 0; q < 4; ++q)
            f[q] = *reinterpret_cast<const float4*>(
                th + lane * 64 + ((q ^ (lane & 3)) * 16));
        // (c) 16 d x 12 lo f64 FMA; W via uniform s_load
        const double* wp = wbase + it * 16;
        double xd[16];
#pragma unroll
        for (int q = 0; q < 4; ++q) {
            xd[q * 4 + 0] = (double)f[q].x;
            xd[q * 4 + 1] = (double)f[q].y;
            xd[q * 4 + 2] = (double)f[q].z;
            xd[q * 4 + 3] = (double)f[q].w;
        }
#pragma unroll
        for (int dd = 0; dd < 16; dd += 4) {
#pragma unroll
            for (int lo = 0; lo < NLO; ++lo) {
                double a = acc[lo];
                a = fma(xd[dd + 0], wp[lo * ND + dd + 0], a);
                a = fma(xd[dd + 1], wp[lo * ND + dd + 1], a);
                a = fma(xd[dd + 2], wp[lo * ND + dd + 2], a);
                a = fma(xd[dd + 3], wp[lo * ND + dd + 3], a);
                acc[lo] = a;
            }
        }
        // (d) write prefetched regs to alternate half (vmcnt waits here)
        if (it < 7) {
            char* tn = tile + ((it + 1) & 1) * 4096;
#pragma unroll
            for (int p = 0; p < 4; ++p) {
                int r = p * 16 + rg;
                *reinterpret_cast<float4*>(tn + r * 64 + ((slot ^ (r & 3)) * 16)) = fr[p];
            }
        }
    }

    // fold 8 d-slices: red overlays the tile space (53248 B <= 65536 B)
    __syncthreads();
    double* red = reinterpret_cast<double*>(buf);
#pragma unroll
    for (int lo = 0; lo < NLO; ++lo)
        red[(wid * 64 + lane) * 13 + lo] = acc[lo];
    __syncthreads();

    if (tid < 192) {                          // thread = (l = tid>>6, row = tid&63)
        const int l = tid >> 6;
        const int rs = tid & 63;
        double proj[NO];
#pragma unroll
        for (int o = 0; o < NO; ++o) {
            int lo = l * NO + o;
            double p0 = 0.0;
#pragma unroll
            for (int w = 0; w < 8; ++w)
                p0 += red[(w * 64 + rs) * 13 + lo];
            proj[o] = p0;
        }
        const long r = row0 + rs;
        const int b = (int)(r >> 12);
        const int t = (int)(r & (NT - 1));
#pragma unroll
        for (int o = 0; o < NO; ++o) {
            double y = proj[o];
            double xx = proj[(o + 3) & 3] + 1e-8;
            double ph = atan2(y, xx);
            if (ph < 0.0) ph += TWO_PI_D;
            double r2 = sqrt(y * y + xx * xx);
            double s, cc;
            if (r2 > 0.0) { s = y / r2; cc = xx / r2; } else { s = 0.0; cc = 1.0; }
            long idx = ((long)((l * NB + b) * NO + o)) * NT + t;
            ws_ph[idx] = ph; ws_s[idx] = (float)s; ws_c[idx] = (float)cc;
        }
    }
}

// ------------- Kernel B: 10 Kuramoto steps, constant-angle rotation ---------
#define B_THREADS 512
#define B_ELEMS (NT / B_THREADS)   // 8

__global__ __launch_bounds__(B_THREADS) void k_kuramoto(
    const float* __restrict__ omegas, const float* __restrict__ Ks,
    double* __restrict__ ws_ph, float* __restrict__ ws_s,
    float* __restrict__ ws_c, double* __restrict__ ws_r,
    float* __restrict__ out_ph)
{
    const int g = blockIdx.x;              // (l*NB + b)*NO + o
    const int l = g >> 5;
    const int b = (g >> 2) & 7;
    const int o = g & 3;
    const double om = (double)omegas[l * NO + o];
    const double Kv = (double)Ks[l];
    const double dtom = DT_D * om;
    const double cKT = DT_D * Kv / (double)NT;  // |eps| <= dt*K/T ~ 5e-5
    double sA, cA; sincos(dtom, &sA, &cA);
    const int tid = threadIdx.x;
    const int wid = tid >> 6;
    const int lane = tid & 63;
    __shared__ double lds[18];

    double ph[B_ELEMS], s[B_ELEMS], c[B_ELEMS];
#pragma unroll
    for (int k = 0; k < B_ELEMS; ++k) {
        long idx = (long)g * NT + tid + k * B_THREADS;
        ph[k] = ws_ph[idx]; s[k] = (double)ws_s[idx]; c[k] = (double)ws_c[idx];
    }

    for (int step = 0; step < NSTEPS; ++step) {
        double ts = 0.0, tc = 0.0;
#pragma unroll
        for (int k = 0; k < B_ELEMS; ++k) { ts += s[k]; tc += c[k]; }
#pragma unroll
        for (int off = 32; off > 0; off >>= 1) {
            ts += __shfl_down(ts, off);
            tc += __shfl_down(tc, off);
        }
        if (lane == 0) { lds[wid] = ts; lds[8 + wid] = tc; }
        __syncthreads();
        if (tid == 0) {
            double S = 0.0, C = 0.0;
#pragma unroll
            for (int w = 0; w < 8; ++w) { S += lds[w]; C += lds[8 + w]; }
            double r2 = sqrt(S * S + C * C);
            double sm, cm;
            if (r2 > 0.0) { sm = S / r2; cm = C / r2; } else { sm = 0.0; cm = 1.0; }
            lds[16] = sm; lds[17] = cm;
        }
        __syncthreads();
        const double sm = lds[16], cm = lds[17];
#pragma unroll
        for (int k = 0; k < B_ELEMS; ++k) {
            double sv = sm * c[k] - cm * s[k];      // sin(mean - ph)
            double eps = cKT * sv;                  // |eps| <= ~5e-5
            double val = ph[k] + (dtom + eps);
            if (val >= TWO_PI_D) val -= TWO_PI_D;   // exact (Sterbenz)
            if (val < 0.0) val += TWO_PI_D;
            ph[k] = val;
            // rotate (s,c) by dtom+eps: sd = sA + cA*eps, cd = cA - sA*eps
            double sd = fma(cA, eps, sA);
            double cd = fma(-sA, eps, cA);
            double sn = fma(s[k], cd, c[k] * sd);
            double cn = fma(c[k], cd, -(s[k] * sd));
            s[k] = sn; c[k] = cn;
        }
        __syncthreads();               // protect lds before next step's writes
    }
    // level coherence from final s,c
    {
        double ts = 0.0, tc = 0.0;
#pragma unroll
        for (int k = 0; k < B_ELEMS; ++k) { ts += s[k]; tc += c[k]; }
#pragma unroll
        for (int off = 32; off > 0; off >>= 1) {
            ts += __shfl_down(ts, off);
            tc += __shfl_down(tc, off);
        }
        if (lane == 0) { lds[wid] = ts; lds[8 + wid] = tc; }
        __syncthreads();
        if (tid == 0) {
            double S = 0.0, C = 0.0;
#pragma unroll
            for (int w = 0; w < 8; ++w) { S += lds[w]; C += lds[8 + w]; }
            double Sm = S / (double)NT, Cm = C / (double)NT;
            ws_r[g] = sqrt(Sm * Sm + Cm * Cm);
        }
    }
#pragma unroll
    for (int k = 0; k < B_ELEMS; ++k) {
        int t = tid + k * B_THREADS;
        long idx = (long)g * NT + t;
        ws_s[idx] = (float)s[k]; ws_c[idx] = (float)c[k];               // final s,c for k_mask
        out_ph[((long)(l * NB + b) * NT + t) * NO + o] = (float)ph[k];  // (L,B,T,O)
    }
}

// ------------- Kernel C: windowed coherence -> boundary mask ----------------
__global__ __launch_bounds__(256) void k_mask(
    const float* __restrict__ ws_s, const float* __restrict__ ws_c,
    float* __restrict__ out_mask)
{
    const int bid = blockIdx.x;            // 24 lb * 16 t-slices
    const int lb = bid >> 4;               // l*NB + b
    const int t0 = ((bid & 15) << 8) + threadIdx.x;
    float* mrow = out_mask + (long)lb * (NT - 2);
    if ((bid & 15) == 0 && threadIdx.x < 2) mrow[threadIdx.x] = 0.0f;
    if (t0 >= NT - 4) return;
    double q[3] = {0.0, 0.0, 0.0};
#pragma unroll
    for (int o = 0; o < NO; ++o) {
        const float* ps = ws_s + ((long)lb * NO + o) * NT + t0;
        const float* pc = ws_c + ((long)lb * NO + o) * NT + t0;
        double sv[5], cv[5];
#pragma unroll
        for (int j = 0; j < 5; ++j) { sv[j] = (double)ps[j]; cv[j] = (double)pc[j]; }
#pragma unroll
        for (int j = 0; j < 3; ++j) {
            double ms = ((sv[j] + sv[j + 1]) + sv[j + 2]) / 3.0;
            double mc = ((cv[j] + cv[j + 1]) + cv[j + 2]) / 3.0;
            q[j] += sqrt(ms * ms + mc * mc);
        }
    }
    double coh0 = q[0] / 4.0, coh1 = q[1] / 4.0, coh2 = q[2] / 4.0;
    bool cond = (coh1 < coh0 - THRESH_D) && (coh1 < coh2 - THRESH_D);
    mrow[2 + t0] = cond ? 1.0f : 0.0f;
}

// ------------- Kernel D: level coherences (24 values) -----------------------
__global__ void k_level(const double* __restrict__ ws_r, float* __restrict__ out_lvl)
{
    const int tid = threadIdx.x;
    if (tid < NB * NL) {
        const int b = tid / NL, l = tid % NL;   // output is (B, L)
        const double* r = ws_r + (long)(l * NB + b) * NO;
        double m = (((r[0] + r[1]) + r[2]) + r[3]) / 4.0;
        out_lvl[tid] = (float)m;
    }
}

extern "C" void kernel_launch(void* const* d_in, const int* in_sizes, int n_in,
                              void* d_out, int out_size, void* d_ws, size_t ws_size,
                              hipStream_t stream)
{
    const float* x      = (const float*)d_in[0];
    const float* W      = (const float*)d_in[1];
    const float* omegas = (const float*)d_in[2];
    const float* Ks     = (const float*)d_in[3];
    float* out = (float*)d_out;

    double* wsW   = (double*)d_ws;                  // 12288 f64
    double* ws_ph = wsW + NLO * ND;                 // 393216 f64
    float*  ws_s  = (float*)(ws_ph + (long)NLO * NB * NT);   // 393216 f32
    float*  ws_c  = ws_s + (long)NLO * NB * NT;              // 393216 f32
    double* ws_r  = (double*)(ws_c + (long)NLO * NB * NT);   // 96 f64

    float* out_ph   = out;            // 393216
    float* out_lvl  = out + 393216;   // 24
    float* out_mask = out + 393240;   // 98256

    k_wprep<<<(NLO * ND + 255) / 256, 256, 0, stream>>>(W, wsW);
    k_proj<<<NB * NT / 64, 512, 0, stream>>>(x, wsW, ws_ph, ws_s, ws_c);
    k_kuramoto<<<NL * NB * NO, B_THREADS, 0, stream>>>(omegas, Ks, ws_ph, ws_s, ws_c, ws_r, out_ph);
    k_mask<<<24 * 16, 256, 0, stream>>>(ws_s, ws_c, out_mask);
    k_level<<<1, 64, 0, stream>>>(ws_r, out_lvl);
}

// Round 9
// 72.302 us; speedup vs baseline: 1.0107x; 1.0107x over previous
//
#include <hip/hip_runtime.h>
#include <math.h>

#define NB 8
#define NT 4096
#define ND 1024
#define NL 3
#define NO 4
#define NLO 12
#define NROWS (NB * NT)          // 32768
#define TWO_PI_D 6.283185307179586476925286766559
#define DT_D 0.1
#define NSTEPS 10
#define THRESH_D 0.3

typedef double f64x4 __attribute__((ext_vector_type(4)));

// ------------- Kernel W-prep: W[12][1024] f32 -> Wt[1024][16] f64 (padded) --
__global__ __launch_bounds__(256) void k_wprep(const float* __restrict__ W,
                                               double* __restrict__ wsWt)
{
    int i = blockIdx.x * 256 + threadIdx.x;   // 0..16383
    if (i < 1024 * 16) {
        int k = i >> 4, col = i & 15;
        wsWt[i] = (col < NLO) ? (double)W[col * ND + k] : 0.0;
    }
}

// ------------- Kernel P: runtime C/D fragment-layout probe ------------------
// Wave computes D = A*B twice with separable inputs:
//  (1) a=lane&15, b=1  -> D[i][j] = 4*i : d/4 gives each (lane,reg)'s ROW
//  (2) a=1, b=lane&15  -> D[i][j] = 4*j : d/4 gives each (lane,reg)'s COL
// Feeding convention matches k_proj (row/col from lane&15, k from lane>>4),
// so any bijective row/col permutation in the true layout self-corrects.
__global__ void k_probe(int* __restrict__ probe)
{
    const int l = threadIdx.x;                // 0..63
    f64x4 z = {0.0, 0.0, 0.0, 0.0};
    double v = (double)(l & 15);
    f64x4 d1 = __builtin_amdgcn_mfma_f64_16x16x4f64(v, 1.0, z, 0, 0, 0);
    f64x4 d2 = __builtin_amdgcn_mfma_f64_16x16x4f64(1.0, v, z, 0, 0, 0);
#pragma unroll
    for (int n = 0; n < 4; ++n) {
        probe[(l * 4 + n) * 2 + 0] = (int)(d1[n] * 0.25 + 0.5);   // row
        probe[(l * 4 + n) * 2 + 1] = (int)(d2[n] * 0.25 + 0.5);   // col
    }
}

// ------------- Kernel A v10: f64 MFMA GEMM with probed epilogue -------------
// Block 256 thr = 4 waves; block owns 64 rows; wave owns a 16-row tile.
// K=1024 in 16 chunks of 64. A: row=lane&15, k=lane>>4 (fed); B: col=lane&15,
// k=lane>>4 (fed). C/D mapping read from probe table (layout-agnostic).
__global__ __launch_bounds__(256) void k_proj(
    const float* __restrict__ x, const double* __restrict__ wsWt,
    const int* __restrict__ probe, double* __restrict__ ws_proj)
{
    __shared__ float  xs[64 * 68];            // 17408 B
    __shared__ double wl[64 * 18];            // 9216 B
    const int tid = threadIdx.x;
    const int lane = tid & 63;
    const int wid = tid >> 6;                 // 0..3
    const long row0 = (long)blockIdx.x * 64;

    const int rg = tid >> 2;                  // staging row 0..63
    const int slot = tid & 3;

    f64x4 acc = {0.0, 0.0, 0.0, 0.0};

    for (int c = 0; c < 16; ++c) {
        if (c) __syncthreads();               // protect LDS reuse
        // stage x chunk: 64 rows x 64 floats (256B/row via 4 thr x 4 float4)
#pragma unroll
        for (int j = 0; j < 4; ++j) {
            float4 v = *reinterpret_cast<const float4*>(
                x + (row0 + rg) * ND + c * 64 + (slot + 4 * j) * 4);
            *reinterpret_cast<float4*>(&xs[rg * 68 + (slot + 4 * j) * 4]) = v;
        }
        // stage Wt chunk: 1024 f64, coalesced read, padded [64][18] write
        const double* wtg = wsWt + (long)c * 64 * 16;
#pragma unroll
        for (int j = 0; j < 4; ++j) {
            int idx = tid + j * 256;
            wl[(idx >> 4) * 18 + (idx & 15)] = wtg[idx];
        }
        __syncthreads();

        const float*  xrow = &xs[(wid * 16 + (lane & 15)) * 68 + (lane >> 4)];
        const double* wrow = &wl[(lane >> 4) * 18 + (lane & 15)];
#pragma unroll
        for (int kc = 0; kc < 16; ++kc) {
            double a = (double)xrow[kc * 4];
            double b = wrow[kc * 4 * 18];
            acc = __builtin_amdgcn_mfma_f64_16x16x4f64(a, b, acc, 0, 0, 0);
        }
    }

    // epilogue: probed (row,col) per (lane,reg) — layout-agnostic scatter
    const int* pr = probe + lane * 8;
#pragma unroll
    for (int n = 0; n < 4; ++n) {
        int i = pr[n * 2 + 0];
        int j = pr[n * 2 + 1];
        if (j < NLO)
            ws_proj[(long)j * NROWS + row0 + wid * 16 + i] = acc[n];
    }
}

// ------------- Kernel B v5: fused phase-init + 10 Kuramoto steps ------------
#define B_THREADS 512
#define B_ELEMS (NT / B_THREADS)   // 8

__global__ __launch_bounds__(B_THREADS) void k_kuramoto(
    const float* __restrict__ omegas, const float* __restrict__ Ks,
    const double* __restrict__ ws_proj, float* __restrict__ ws_s,
    float* __restrict__ ws_c, double* __restrict__ ws_r,
    float* __restrict__ out_ph)
{
    const int g = blockIdx.x;              // (l*NB + b)*NO + o
    const int l = g >> 5;
    const int b = (g >> 2) & 7;
    const int o = g & 3;
    const double om = (double)omegas[l * NO + o];
    const double Kv = (double)Ks[l];
    const double dtom = DT_D * om;
    const double cKT = DT_D * Kv / (double)NT;  // |eps| <= dt*K/T ~ 5e-5
    double sA, cA; sincos(dtom, &sA, &cA);
    const int tid = threadIdx.x;
    const int wid = tid >> 6;
    const int lane = tid & 63;
    __shared__ double lds[16];

    // fused phase init from proj columns (contiguous reads)
    const double* pA = ws_proj + (long)(l * NO + o) * NROWS + (long)b * NT;
    const double* pB = ws_proj + (long)(l * NO + ((o + 3) & 3)) * NROWS + (long)b * NT;

    double ph[B_ELEMS], s[B_ELEMS], c[B_ELEMS];
#pragma unroll
    for (int k = 0; k < B_ELEMS; ++k) {
        int t = tid + k * B_THREADS;
        double y = pA[t];
        double xx = pB[t] + 1e-8;
        double p = atan2(y, xx);
        if (p < 0.0) p += TWO_PI_D;
        ph[k] = p;
        double r2 = sqrt(y * y + xx * xx);
        if (r2 > 0.0) { s[k] = y / r2; c[k] = xx / r2; }
        else          { s[k] = 0.0;    c[k] = 1.0; }
    }

    for (int step = 0; step < NSTEPS; ++step) {
        double ts = 0.0, tc = 0.0;
#pragma unroll
        for (int k = 0; k < B_ELEMS; ++k) { ts += s[k]; tc += c[k]; }
#pragma unroll
        for (int off = 32; off > 0; off >>= 1) {
            ts += __shfl_down(ts, off);
            tc += __shfl_down(tc, off);
        }
        if (lane == 0) { lds[wid] = ts; lds[8 + wid] = tc; }
        __syncthreads();
        // every thread redundantly folds the 8 partials (no serial section)
        double S = 0.0, C = 0.0;
#pragma unroll
        for (int w = 0; w < 8; ++w) { S += lds[w]; C += lds[8 + w]; }
        double rr = sqrt(S * S + C * C);
        double sm, cm;
        if (rr > 0.0) { sm = S / rr; cm = C / rr; } else { sm = 0.0; cm = 1.0; }
#pragma unroll
        for (int k = 0; k < B_ELEMS; ++k) {
            double sv = sm * c[k] - cm * s[k];      // sin(mean - ph)
            double eps = cKT * sv;                  // |eps| <= ~5e-5
            double val = ph[k] + (dtom + eps);
            if (val >= TWO_PI_D) val -= TWO_PI_D;   // exact (Sterbenz)
            if (val < 0.0) val += TWO_PI_D;
            ph[k] = val;
            // rotate (s,c) by dtom+eps: sd = sA + cA*eps, cd = cA - sA*eps
            double sd = fma(cA, eps, sA);
            double cd = fma(-sA, eps, cA);
            double sn = fma(s[k], cd, c[k] * sd);
            double cn = fma(c[k], cd, -(s[k] * sd));
            s[k] = sn; c[k] = cn;
        }
        __syncthreads();               // protect lds before next step's writes
    }
    // level coherence from final s,c
    {
        double ts = 0.0, tc = 0.0;
#pragma unroll
        for (int k = 0; k < B_ELEMS; ++k) { ts += s[k]; tc += c[k]; }
#pragma unroll
        for (int off = 32; off > 0; off >>= 1) {
            ts += __shfl_down(ts, off);
            tc += __shfl_down(tc, off);
        }
        if (lane == 0) { lds[wid] = ts; lds[8 + wid] = tc; }
        __syncthreads();
        if (tid == 0) {
            double S = 0.0, C = 0.0;
#pragma unroll
            for (int w = 0; w < 8; ++w) { S += lds[w]; C += lds[8 + w]; }
            double Sm = S / (double)NT, Cm = C / (double)NT;
            ws_r[g] = sqrt(Sm * Sm + Cm * Cm);
        }
    }
#pragma unroll
    for (int k = 0; k < B_ELEMS; ++k) {
        int t = tid + k * B_THREADS;
        long idx = (long)g * NT + t;
        ws_s[idx] = (float)s[k]; ws_c[idx] = (float)c[k];               // for k_mask
        out_ph[((long)(l * NB + b) * NT + t) * NO + o] = (float)ph[k];  // (L,B,T,O)
    }
}

// ------------- Kernel C: windowed coherence -> boundary mask ----------------
__global__ __launch_bounds__(256) void k_mask(
    const float* __restrict__ ws_s, const float* __restrict__ ws_c,
    float* __restrict__ out_mask)
{
    const int bid = blockIdx.x;            // 24 lb * 16 t-slices
    const int lb = bid >> 4;               // l*NB + b
    const int t0 = ((bid & 15) << 8) + threadIdx.x;
    float* mrow = out_mask + (long)lb * (NT - 2);
    if ((bid & 15) == 0 && threadIdx.x < 2) mrow[threadIdx.x] = 0.0f;
    if (t0 >= NT - 4) return;
    double q[3] = {0.0, 0.0, 0.0};
#pragma unroll
    for (int o = 0; o < NO; ++o) {
        const float* ps = ws_s + ((long)lb * NO + o) * NT + t0;
        const float* pc = ws_c + ((long)lb * NO + o) * NT + t0;
        double sv[5], cv[5];
#pragma unroll
        for (int j = 0; j < 5; ++j) { sv[j] = (double)ps[j]; cv[j] = (double)pc[j]; }
#pragma unroll
        for (int j = 0; j < 3; ++j) {
            double ms = ((sv[j] + sv[j + 1]) + sv[j + 2]) / 3.0;
            double mc = ((cv[j] + cv[j + 1]) + cv[j + 2]) / 3.0;
            q[j] += sqrt(ms * ms + mc * mc);
        }
    }
    double coh0 = q[0] / 4.0, coh1 = q[1] / 4.0, coh2 = q[2] / 4.0;
    bool cond = (coh1 < coh0 - THRESH_D) && (coh1 < coh2 - THRESH_D);
    mrow[2 + t0] = cond ? 1.0f : 0.0f;
}

// ------------- Kernel D: level coherences (24 values) -----------------------
__global__ void k_level(const double* __restrict__ ws_r, float* __restrict__ out_lvl)
{
    const int tid = threadIdx.x;
    if (tid < NB * NL) {
        const int b = tid / NL, l = tid % NL;   // output is (B, L)
        const double* r = ws_r + (long)(l * NB + b) * NO;
        double m = (((r[0] + r[1]) + r[2]) + r[3]) / 4.0;
        out_lvl[tid] = (float)m;
    }
}

extern "C" void kernel_launch(void* const* d_in, const int* in_sizes, int n_in,
                              void* d_out, int out_size, void* d_ws, size_t ws_size,
                              hipStream_t stream)
{
    const float* x      = (const float*)d_in[0];
    const float* W      = (const float*)d_in[1];
    const float* omegas = (const float*)d_in[2];
    const float* Ks     = (const float*)d_in[3];
    float* out = (float*)d_out;

    double* wsWt    = (double*)d_ws;                   // 16384 f64 (128 KB)
    double* ws_proj = wsWt + 1024 * 16;                // 12*32768 f64 (3 MB)
    float*  ws_s    = (float*)(ws_proj + (long)NLO * NROWS);  // 393216 f32
    float*  ws_c    = ws_s + (long)NLO * NB * NT;             // 393216 f32
    double* ws_r    = (double*)(ws_c + (long)NLO * NB * NT);  // 96 f64
    int*    probe   = (int*)(ws_r + 96);                      // 512 ints

    float* out_ph   = out;            // 393216
    float* out_lvl  = out + 393216;   // 24
    float* out_mask = out + 393240;   // 98256

    k_wprep<<<64, 256, 0, stream>>>(W, wsWt);
    k_probe<<<1, 64, 0, stream>>>(probe);
    k_proj<<<NROWS / 64, 256, 0, stream>>>(x, wsWt, probe, ws_proj);
    k_kuramoto<<<NL * NB * NO, B_THREADS, 0, stream>>>(omegas, Ks, ws_proj, ws_s, ws_c, ws_r, out_ph);
    k_mask<<<24 * 16, 256, 0, stream>>>(ws_s, ws_c, out_mask);
    k_level<<<1, 64, 0, stream>>>(ws_r, out_lvl);
}

// Round 10
// 70.306 us; speedup vs baseline: 1.0394x; 1.0284x over previous
//
#include <hip/hip_runtime.h>
#include <math.h>

#define NB 8
#define NT 4096
#define ND 1024
#define NL 3
#define NO 4
#define NLO 12
#define NROWS (NB * NT)          // 32768
#define TWO_PI_D 6.283185307179586476925286766559
#define DT_D 0.1
#define NSTEPS 10
#define THRESH_D 0.3

typedef double f64x4 __attribute__((ext_vector_type(4)));

// ------------- Kernel W-prep: W[12][1024] f32 -> Wt[1024][16] f64 (padded) --
__global__ __launch_bounds__(256) void k_wprep(const float* __restrict__ W,
                                               double* __restrict__ wsWt)
{
    int i = blockIdx.x * 256 + threadIdx.x;   // 0..16383
    if (i < 1024 * 16) {
        int k = i >> 4, col = i & 15;
        wsWt[i] = (col < NLO) ? (double)W[col * ND + k] : 0.0;
    }
}

// ------------- Kernel A v11: f64 MFMA GEMM, occupancy-first schedule --------
// 1024 blocks x 512 thr (8 waves). Block owns 32 rows; wave = (tile=wid&1:
// 16 rows, kq=wid>>1: K-quarter of 256). 4 rounds: stage x[32 x 4 windows of
// 64 cols] to LDS (stride 68: b128 writes conflict-free, b32 reads 2-way);
// each wave does one 64-k chunk = 16 MFMAs, B operand read directly from the
// L2-resident Wt table (16-lane groups = contiguous 128B). launch_bounds
// (512,6) -> 6 waves/SIMD to hide the stage/barrier drain (R6 showed source-
// level pipelining is null here; occupancy is the lever). Probe MFMAs inlined.
__global__ __launch_bounds__(512, 6) void k_proj(
    const float* __restrict__ x, const double* __restrict__ wsWt,
    double* __restrict__ ws_proj)
{
    __shared__ char buf[4 * 32 * 68 * 4];     // 34816 B (xs; reused as red)
    float*  xs  = reinterpret_cast<float*>(buf);
    double* red = reinterpret_cast<double*>(buf);

    const int tid  = threadIdx.x;
    const int lane = tid & 63;
    const int wid  = tid >> 6;                // 0..7
    const int tile = wid & 1;                 // row-tile (16 rows)
    const int kq   = wid >> 1;                // K-quarter
    const long row0 = (long)blockIdx.x * 32;

    f64x4 acc = {0.0, 0.0, 0.0, 0.0};

    for (int r = 0; r < 4; ++r) {
        if (r) __syncthreads();
        // stage 4 windows: window w covers cols [w*256 + r*64, +64) of 32 rows
#pragma unroll
        for (int p = 0; p < 4; ++p) {
            int idx = tid + p * 512;          // 0..2047
            int w   = idx >> 9;
            int row = (idx >> 4) & 31;
            int sl  = idx & 15;
            float4 v = *reinterpret_cast<const float4*>(
                x + (row0 + row) * ND + w * 256 + r * 64 + sl * 4);
            *reinterpret_cast<float4*>(&xs[(w * 32 + row) * 68 + sl * 4]) = v;
        }
        __syncthreads();

        // A from LDS (row = lane&15, k-group = lane>>4); B direct from L2.
        const float* arow =
            &xs[(kq * 32 + tile * 16 + (lane & 15)) * 68 + (lane >> 4)];
        const double* wb =
            wsWt + (long)(kq * 256 + r * 64 + (lane >> 4)) * 16 + (lane & 15);

        double bv[4], bn[4];
#pragma unroll
        for (int q = 0; q < 4; ++q) bv[q] = wb[q * 64];
#pragma unroll
        for (int g = 0; g < 4; ++g) {
            if (g < 3) {
#pragma unroll
                for (int q = 0; q < 4; ++q) bn[q] = wb[(g * 4 + 4 + q) * 64];
            }
#pragma unroll
            for (int q = 0; q < 4; ++q) {
                double a = (double)arow[(g * 4 + q) * 4];
                acc = __builtin_amdgcn_mfma_f64_16x16x4f64(a, bv[q], acc, 0, 0, 0);
            }
#pragma unroll
            for (int q = 0; q < 4; ++q) bv[q] = bn[q];
        }
    }

    // inline C/D layout probe (separable inputs; same feed convention)
    f64x4 z = {0.0, 0.0, 0.0, 0.0};
    f64x4 d1 = __builtin_amdgcn_mfma_f64_16x16x4f64((double)(lane & 15), 1.0, z, 0, 0, 0);
    f64x4 d2 = __builtin_amdgcn_mfma_f64_16x16x4f64(1.0, (double)(lane & 15), z, 0, 0, 0);

    // 4-way K-fold through LDS (reuse xs as red[8][64][4] f64 = 16 KB)
    __syncthreads();
#pragma unroll
    for (int n = 0; n < 4; ++n)
        red[(wid * 64 + lane) * 4 + n] = acc[n];
    __syncthreads();
    if (kq == 0) {
#pragma unroll
        for (int n = 0; n < 4; ++n) {
            double v = (red[((0 + tile) * 64 + lane) * 4 + n] +
                        red[((2 + tile) * 64 + lane) * 4 + n]) +
                       (red[((4 + tile) * 64 + lane) * 4 + n] +
                        red[((6 + tile) * 64 + lane) * 4 + n]);
            int i = (int)(d1[n] * 0.25 + 0.5);
            int j = (int)(d2[n] * 0.25 + 0.5);
            if (j < NLO)
                ws_proj[(long)j * NROWS + row0 + tile * 16 + i] = v;
        }
    }
}

// ------------- Kernel B v5: fused phase-init + 10 Kuramoto steps ------------
#define B_THREADS 512
#define B_ELEMS (NT / B_THREADS)   // 8

__global__ __launch_bounds__(B_THREADS) void k_kuramoto(
    const float* __restrict__ omegas, const float* __restrict__ Ks,
    const double* __restrict__ ws_proj, float* __restrict__ ws_s,
    float* __restrict__ ws_c, double* __restrict__ ws_r,
    float* __restrict__ out_ph)
{
    const int g = blockIdx.x;              // (l*NB + b)*NO + o
    const int l = g >> 5;
    const int b = (g >> 2) & 7;
    const int o = g & 3;
    const double om = (double)omegas[l * NO + o];
    const double Kv = (double)Ks[l];
    const double dtom = DT_D * om;
    const double cKT = DT_D * Kv / (double)NT;  // |eps| <= dt*K/T ~ 5e-5
    double sA, cA; sincos(dtom, &sA, &cA);
    const int tid = threadIdx.x;
    const int wid = tid >> 6;
    const int lane = tid & 63;
    __shared__ double lds[16];

    // fused phase init from proj columns (contiguous reads)
    const double* pA = ws_proj + (long)(l * NO + o) * NROWS + (long)b * NT;
    const double* pB = ws_proj + (long)(l * NO + ((o + 3) & 3)) * NROWS + (long)b * NT;

    double ph[B_ELEMS], s[B_ELEMS], c[B_ELEMS];
#pragma unroll
    for (int k = 0; k < B_ELEMS; ++k) {
        int t = tid + k * B_THREADS;
        double y = pA[t];
        double xx = pB[t] + 1e-8;
        double p = atan2(y, xx);
        if (p < 0.0) p += TWO_PI_D;
        ph[k] = p;
        double r2 = sqrt(y * y + xx * xx);
        if (r2 > 0.0) { s[k] = y / r2; c[k] = xx / r2; }
        else          { s[k] = 0.0;    c[k] = 1.0; }
    }

    for (int step = 0; step < NSTEPS; ++step) {
        double ts = 0.0, tc = 0.0;
#pragma unroll
        for (int k = 0; k < B_ELEMS; ++k) { ts += s[k]; tc += c[k]; }
#pragma unroll
        for (int off = 32; off > 0; off >>= 1) {
            ts += __shfl_down(ts, off);
            tc += __shfl_down(tc, off);
        }
        if (lane == 0) { lds[wid] = ts; lds[8 + wid] = tc; }
        __syncthreads();
        // every thread redundantly folds the 8 partials (no serial section)
        double S = 0.0, C = 0.0;
#pragma unroll
        for (int w = 0; w < 8; ++w) { S += lds[w]; C += lds[8 + w]; }
        double rr = sqrt(S * S + C * C);
        double sm, cm;
        if (rr > 0.0) { sm = S / rr; cm = C / rr; } else { sm = 0.0; cm = 1.0; }
#pragma unroll
        for (int k = 0; k < B_ELEMS; ++k) {
            double sv = sm * c[k] - cm * s[k];      // sin(mean - ph)
            double eps = cKT * sv;                  // |eps| <= ~5e-5
            double val = ph[k] + (dtom + eps);
            if (val >= TWO_PI_D) val -= TWO_PI_D;   // exact (Sterbenz)
            if (val < 0.0) val += TWO_PI_D;
            ph[k] = val;
            // rotate (s,c) by dtom+eps: sd = sA + cA*eps, cd = cA - sA*eps
            double sd = fma(cA, eps, sA);
            double cd = fma(-sA, eps, cA);
            double sn = fma(s[k], cd, c[k] * sd);
            double cn = fma(c[k], cd, -(s[k] * sd));
            s[k] = sn; c[k] = cn;
        }
        __syncthreads();               // protect lds before next step's writes
    }
    // level coherence from final s,c
    {
        double ts = 0.0, tc = 0.0;
#pragma unroll
        for (int k = 0; k < B_ELEMS; ++k) { ts += s[k]; tc += c[k]; }
#pragma unroll
        for (int off = 32; off > 0; off >>= 1) {
            ts += __shfl_down(ts, off);
            tc += __shfl_down(tc, off);
        }
        if (lane == 0) { lds[wid] = ts; lds[8 + wid] = tc; }
        __syncthreads();
        if (tid == 0) {
            double S = 0.0, C = 0.0;
#pragma unroll
            for (int w = 0; w < 8; ++w) { S += lds[w]; C += lds[8 + w]; }
            double Sm = S / (double)NT, Cm = C / (double)NT;
            ws_r[g] = sqrt(Sm * Sm + Cm * Cm);
        }
    }
#pragma unroll
    for (int k = 0; k < B_ELEMS; ++k) {
        int t = tid + k * B_THREADS;
        long idx = (long)g * NT + t;
        ws_s[idx] = (float)s[k]; ws_c[idx] = (float)c[k];               // for k_mask
        out_ph[((long)(l * NB + b) * NT + t) * NO + o] = (float)ph[k];  // (L,B,T,O)
    }
}

// ------------- Kernel C: windowed coherence -> boundary mask ----------------
__global__ __launch_bounds__(256) void k_mask(
    const float* __restrict__ ws_s, const float* __restrict__ ws_c,
    float* __restrict__ out_mask)
{
    const int bid = blockIdx.x;            // 24 lb * 16 t-slices
    const int lb = bid >> 4;               // l*NB + b
    const int t0 = ((bid & 15) << 8) + threadIdx.x;
    float* mrow = out_mask + (long)lb * (NT - 2);
    if ((bid & 15) == 0 && threadIdx.x < 2) mrow[threadIdx.x] = 0.0f;
    if (t0 >= NT - 4) return;
    double q[3] = {0.0, 0.0, 0.0};
#pragma unroll
    for (int o = 0; o < NO; ++o) {
        const float* ps = ws_s + ((long)lb * NO + o) * NT + t0;
        const float* pc = ws_c + ((long)lb * NO + o) * NT + t0;
        double sv[5], cv[5];
#pragma unroll
        for (int j = 0; j < 5; ++j) { sv[j] = (double)ps[j]; cv[j] = (double)pc[j]; }
#pragma unroll
        for (int j = 0; j < 3; ++j) {
            double ms = ((sv[j] + sv[j + 1]) + sv[j + 2]) / 3.0;
            double mc = ((cv[j] + cv[j + 1]) + cv[j + 2]) / 3.0;
            q[j] += sqrt(ms * ms + mc * mc);
        }
    }
    double coh0 = q[0] / 4.0, coh1 = q[1] / 4.0, coh2 = q[2] / 4.0;
    bool cond = (coh1 < coh0 - THRESH_D) && (coh1 < coh2 - THRESH_D);
    mrow[2 + t0] = cond ? 1.0f : 0.0f;
}

// ------------- Kernel D: level coherences (24 values) -----------------------
__global__ void k_level(const double* __restrict__ ws_r, float* __restrict__ out_lvl)
{
    const int tid = threadIdx.x;
    if (tid < NB * NL) {
        const int b = tid / NL, l = tid % NL;   // output is (B, L)
        const double* r = ws_r + (long)(l * NB + b) * NO;
        double m = (((r[0] + r[1]) + r[2]) + r[3]) / 4.0;
        out_lvl[tid] = (float)m;
    }
}

extern "C" void kernel_launch(void* const* d_in, const int* in_sizes, int n_in,
                              void* d_out, int out_size, void* d_ws, size_t ws_size,
                              hipStream_t stream)
{
    const float* x      = (const float*)d_in[0];
    const float* W      = (const float*)d_in[1];
    const float* omegas = (const float*)d_in[2];
    const float* Ks     = (const float*)d_in[3];
    float* out = (float*)d_out;

    double* wsWt    = (double*)d_ws;                   // 16384 f64 (128 KB)
    double* ws_proj = wsWt + 1024 * 16;                // 12*32768 f64 (3 MB)
    float*  ws_s    = (float*)(ws_proj + (long)NLO * NROWS);  // 393216 f32
    float*  ws_c    = ws_s + (long)NLO * NB * NT;             // 393216 f32
    double* ws_r    = (double*)(ws_c + (long)NLO * NB * NT);  // 96 f64

    float* out_ph   = out;            // 393216
    float* out_lvl  = out + 393216;   // 24
    float* out_mask = out + 393240;   // 98256

    k_wprep<<<64, 256, 0, stream>>>(W, wsWt);
    k_proj<<<NROWS / 32, 512, 0, stream>>>(x, wsWt, ws_proj);
    k_kuramoto<<<NL * NB * NO, B_THREADS, 0, stream>>>(omegas, Ks, ws_proj, ws_s, ws_c, ws_r, out_ph);
    k_mask<<<24 * 16, 256, 0, stream>>>(ws_s, ws_c, out_mask);
    k_level<<<1, 64, 0, stream>>>(ws_r, out_lvl);
}